// Round 5
// baseline (741.278 us; speedup 1.0000x reference)
//
#include <hip/hip_runtime.h>
#include <math.h>

// Problem constants
constexpr int Bc  = 8;
constexpr int Nn  = 1024;
constexpr int Dd  = 512;
constexpr int Hh  = 8;
constexpr int HD  = 64;
constexpr float SCALE = 0.125f; // 1/sqrt(64)

typedef unsigned short ushort_t;
typedef unsigned int uint32;
typedef __attribute__((ext_vector_type(8))) short short8;   // 8 bf16 (4 VGPRs)
typedef __attribute__((ext_vector_type(4))) float f32x4;

// ---------------- bf16 split helpers (round-to-nearest-even) ----------------
__device__ __forceinline__ uint32 bf16rn(float x) {
  uint32 u = __float_as_uint(x);
  return (u + 0x7FFFu + ((u >> 16) & 1u)) >> 16;
}
__device__ __forceinline__ float bf16up(uint32 h) { return __uint_as_float(h << 16); }

__device__ __forceinline__ void split8(const float* xs, uint4& hi, uint4& lo) {
  uint32 h[8], l[8];
#pragma unroll
  for (int j = 0; j < 8; ++j) {
    h[j] = bf16rn(xs[j]);
    l[j] = bf16rn(xs[j] - bf16up(h[j]));
  }
  hi.x = h[0] | (h[1] << 16); hi.y = h[2] | (h[3] << 16);
  hi.z = h[4] | (h[5] << 16); hi.w = h[6] | (h[7] << 16);
  lo.x = l[0] | (l[1] << 16); lo.y = l[2] | (l[3] << 16);
  lo.z = l[4] | (l[5] << 16); lo.w = l[6] | (l[7] << 16);
}

// node_valid_mask may arrive as 1-byte bool or 4-byte int/float.
__device__ __forceinline__ bool lane_valid(const unsigned char* m8, bool bytelay, int idx) {
  if (bytelay) return m8[idx] != 0;
  return ((const int*)m8)[idx] != 0;
}

// ---------------------------------------------------------------------------
// Convert fp32 [R][512] -> MFMA-fragment-tiled split bf16:
// layout [R/16][16 ksteps][2 hi/lo][512] ushort. Used for x, aout, qkv_w, out_w
// (A-side and B-side fragments share the same layout).
// ---------------------------------------------------------------------------
__global__ __launch_bounds__(256) void convert_split(
    const float* __restrict__ src, ushort_t* __restrict__ dst)
{
  const int t    = blockIdx.x * 256 + threadIdx.x;
  const int lane = t & 63;
  const int blk  = t >> 6;            // rt*16 + ks
  const int rt   = blk >> 4, ks = blk & 15;
  const int row  = rt * 16 + (lane & 15);
  const int k    = ks * 32 + (lane >> 4) * 8;

  const float* s = src + (size_t)row * 512 + k;
  float4 a = *(const float4*)s, b = *(const float4*)(s + 4);
  float xs[8] = {a.x, a.y, a.z, a.w, b.x, b.y, b.z, b.w};
  uint4 hi, lo; split8(xs, hi, lo);

  ushort_t* d = dst + (size_t)blk * 1024 + lane * 8;
  *(uint4*)d = hi;
  *(uint4*)(d + 512) = lo;
}

// ---------------------------------------------------------------------------
// Convert q/k fp32 [rows][64] (rows = bh*1024 + token) into A/B-operand
// fragment tiles: [rows/16][2 ks][2 hl][512] ushort.
// ---------------------------------------------------------------------------
__global__ __launch_bounds__(256) void convert_frag_qk(
    const float* __restrict__ src, ushort_t* __restrict__ dst)
{
  const int t    = blockIdx.x * 256 + threadIdx.x;
  const int lane = t & 63;
  const int fid  = t >> 6;           // tile*2 + ks
  const int tile = fid >> 1, ks = fid & 1;
  const int row  = tile * 16 + (lane & 15);
  const int d    = ks * 32 + (lane >> 4) * 8;

  const float* s = src + (size_t)row * HD + d;
  float4 a = *(const float4*)s, b = *(const float4*)(s + 4);
  float xs[8] = {a.x, a.y, a.z, a.w, b.x, b.y, b.z, b.w};
  uint4 hi, lo; split8(xs, hi, lo);

  ushort_t* dp = dst + (size_t)fid * 1024 + lane * 8;
  *(uint4*)dp = hi;
  *(uint4*)(dp + 512) = lo;
}

// ---------------------------------------------------------------------------
// Convert v fp32 [bh][1024 key][64 d] into PV B-operand fragments:
// [bh][16 kt][2 ks][4 dt][2 hl][512].
// ---------------------------------------------------------------------------
__global__ __launch_bounds__(256) void convert_frag_v(
    const float* __restrict__ src, ushort_t* __restrict__ dst)
{
  const int t    = blockIdx.x * 256 + threadIdx.x;
  const int lane = t & 63;
  const int fid  = t >> 6;           // ((bh*16+kt)*2+ks)*4+dt
  const int dt   = fid & 3;
  const int ks   = (fid >> 2) & 1;
  const int kt   = (fid >> 3) & 15;
  const int bh   = fid >> 7;
  const int d    = dt * 16 + (lane & 15);
  const int key0 = kt * 64 + ks * 32 + (lane >> 4) * 8;

  const float* s = src + ((size_t)bh * Nn + key0) * HD + d;
  float xs[8];
#pragma unroll
  for (int j = 0; j < 8; ++j) xs[j] = s[(size_t)j * HD];
  uint4 hi, lo; split8(xs, hi, lo);

  ushort_t* dp = dst + (size_t)fid * 1024 + lane * 8;
  *(uint4*)dp = hi;
  *(uint4*)(dp + 512) = lo;
}

// ---------------------------------------------------------------------------
// bf16x3 MFMA GEMM, both operands pre-fragged: C = A[Mx512]*W[Ncolsx512]^T + b.
// Block: 128 x BN C tile, 256 threads = 4 waves (2x2). Staging is pure uint4
// copy (no inline conversion). SCATTER writes qkv into q/k/v [B,H,N,HD].
// ---------------------------------------------------------------------------
template<int BN, bool SCATTER>
__global__ __launch_bounds__(256) void gemm_f(
    const ushort_t* __restrict__ Ac, const ushort_t* __restrict__ Bfrag,
    const float* __restrict__ bias, float* __restrict__ C, int Ncols,
    float* __restrict__ qb, float* __restrict__ kb, float* __restrict__ vb)
{
  constexpr int NT   = BN / 32;        // col tiles per wave (2 or 4)
  constexpr int BCH  = (BN / 16) * 2;  // B chunks per kt
  __shared__ ushort_t Ablk[16 * 512];
  __shared__ ushort_t Bblk[BCH * 512];

  const int t = threadIdx.x, lane = t & 63, w = t >> 6;
  const int wr = w >> 1, wc = w & 1;
  const int j0 = blockIdx.x * BN, i0 = blockIdx.y * 128;

  f32x4 acc[4][NT];
#pragma unroll
  for (int a = 0; a < 4; ++a)
#pragma unroll
    for (int b = 0; b < NT; ++b) acc[a][b] = (f32x4){0.f, 0.f, 0.f, 0.f};

  for (int kt = 0; kt < 16; ++kt) {
    __syncthreads();
    // stage A (16 chunks) + B (BCH chunks), 1 KB each, pure copies
#pragma unroll
    for (int ci = 0; ci < (16 + BCH) / 4; ++ci) {
      const int c = ci * 4 + w;
      const ushort_t* src;
      ushort_t* dst;
      if (c < 16) {
        const int rt = c >> 1, hl = c & 1;
        src = Ac + (((size_t)((i0 >> 4) + rt) * 16 + kt)) * 1024 + hl * 512 + lane * 8;
        dst = Ablk + c * 512 + lane * 8;
      } else {
        const int cb = c - 16, bt = cb >> 1, hl = cb & 1;
        src = Bfrag + (((size_t)((j0 >> 4) + bt) * 16 + kt)) * 1024 + hl * 512 + lane * 8;
        dst = Bblk + cb * 512 + lane * 8;
      }
      *(uint4*)dst = *(const uint4*)src;
    }
    __syncthreads();

    const ushort_t* Ab = Ablk + (size_t)(wr * 4) * 1024 + lane * 8;
    short8 Ah[4], Al[4];
#pragma unroll
    for (int ti = 0; ti < 4; ++ti) {
      Ah[ti] = *(const short8*)(Ab + ti * 1024);
      Al[ti] = *(const short8*)(Ab + ti * 1024 + 512);
    }
#pragma unroll
    for (int ct = 0; ct < NT; ++ct) {
      const ushort_t* Bb = Bblk + (size_t)(wc * NT + ct) * 1024 + lane * 8;
      short8 Bh = *(const short8*)Bb;
      short8 Bl = *(const short8*)(Bb + 512);
#pragma unroll
      for (int ti = 0; ti < 4; ++ti) {
        acc[ti][ct] = __builtin_amdgcn_mfma_f32_16x16x32_bf16(Ah[ti], Bh, acc[ti][ct], 0, 0, 0);
        acc[ti][ct] = __builtin_amdgcn_mfma_f32_16x16x32_bf16(Al[ti], Bh, acc[ti][ct], 0, 0, 0);
        acc[ti][ct] = __builtin_amdgcn_mfma_f32_16x16x32_bf16(Ah[ti], Bl, acc[ti][ct], 0, 0, 0);
      }
    }
  }

  const int rbase = i0 + wr * 64 + (lane >> 4) * 4;
  const int cb0   = j0 + wc * (NT * 16) + (lane & 15);
#pragma unroll
  for (int ct = 0; ct < NT; ++ct) {
    const int col = cb0 + ct * 16;
    const float bv = bias[col];
    float* dst = nullptr;
    if (SCATTER) {
      const int s = col >> 9, h = (col >> 6) & 7;
      dst  = (s == 0) ? qb : (s == 1) ? kb : vb;
      dst += (size_t)h * Nn * HD + (col & 63);
    }
#pragma unroll
    for (int ti = 0; ti < 4; ++ti) {
      const int r0 = rbase + ti * 16;
#pragma unroll
      for (int r = 0; r < 4; ++r) {
        const float v = acc[ti][ct][r] + bv;
        const int row = r0 + r;
        if (SCATTER) {
          const int b2 = row >> 10, n = row & 1023;
          dst[((size_t)b2 * Hh * Nn + n) * HD] = v;
        } else {
          C[(size_t)row * Ncols + col] = v;
        }
      }
    }
  }
}

// ---------------------------------------------------------------------------
// MFMA flash attention. Block = (bh, 64-q tile); 4 independent waves, each
// owning 16 queries; no __syncthreads. Bias: coalesced float4 loads,
// register-prefetched one K-tile ahead, redistributed via per-wave padded
// LDS tile (stride 68 -> conflict-free reads). P frags via per-wave LDS.
// ---------------------------------------------------------------------------
__global__ __launch_bounds__(256) void attn_mfma(
    const ushort_t* __restrict__ qf, const ushort_t* __restrict__ kf,
    const ushort_t* __restrict__ vf, const float* __restrict__ bias,
    const unsigned char* __restrict__ m8, float* __restrict__ outp)
{
  __shared__ float sbuf[4][2][1088];   // [wave][0 = bias 16x68 | 1 = P frags]

  const int t = threadIdx.x, lane = t & 63, w = t >> 6;
  const int bx = blockIdx.x;
  const int qt = bx & 15, bh = bx >> 4;
  const int b = bh >> 3, h = bh & 7;
  const int tt = qt * 4 + w;           // 16-query tile: 0..63
  const int q0 = tt * 16;
  const bool bytelay = (m8[1] != 0);

  // Q fragments (held for the whole kernel)
  short8 Qh[2], Ql[2];
#pragma unroll
  for (int ks = 0; ks < 2; ++ks) {
    const ushort_t* qp = qf + ((size_t)(bh * 64 + tt) * 2 + ks) * 1024 + lane * 8;
    Qh[ks] = *(const short8*)qp;
    Ql[ks] = *(const short8*)(qp + 512);
  }

  f32x4 Oacc[4];
#pragma unroll
  for (int dt = 0; dt < 4; ++dt) Oacc[dt] = (f32x4){0.f, 0.f, 0.f, 0.f};
  float m_run[4], l_run[4];
#pragma unroll
  for (int r = 0; r < 4; ++r) { m_run[r] = -__builtin_inff(); l_run[r] = 0.f; }

  float*    bb = &sbuf[w][0][0];
  ushort_t* pb = (ushort_t*)&sbuf[w][1][0];

  // bias base: row q0+(lane>>4)*4, col (lane&15)*4
  const float* bp0 = bias + ((size_t)bh * Nn + q0 + (lane >> 4) * 4) * Nn + (lane & 15) * 4;

  // pipeline: breg holds bias tile kt at loop top (if tile valid)
  unsigned long long km_cur = __ballot(lane_valid(m8, bytelay, b * Nn + lane));
  float4 breg[4] = {};
  if (km_cur) {
#pragma unroll
    for (int i = 0; i < 4; ++i) breg[i] = *(const float4*)(bp0 + (size_t)i * Nn);
  }

  for (int kt = 0; kt < 16; ++kt) {
    unsigned long long km_next = 0ull;
    if (kt < 15)
      km_next = __ballot(lane_valid(m8, bytelay, b * Nn + (kt + 1) * 64 + lane));
    float4 bnext[4] = {};
    if (km_next) {
      const float* bp = bp0 + (size_t)(kt + 1) * 64;
#pragma unroll
      for (int i = 0; i < 4; ++i) bnext[i] = *(const float4*)(bp + (size_t)i * Nn);
    }

    if (km_cur) {
      // bias regs -> LDS (coalesced-loaded layout [row][68])
#pragma unroll
      for (int i = 0; i < 4; ++i)
        *(float4*)&bb[((lane >> 4) * 4 + i) * 68 + (lane & 15) * 4] = breg[i];

      // S = Q*K^T (x3)
      f32x4 Sacc[4];
#pragma unroll
      for (int nt = 0; nt < 4; ++nt) Sacc[nt] = (f32x4){0.f, 0.f, 0.f, 0.f};
#pragma unroll
      for (int ks = 0; ks < 2; ++ks)
#pragma unroll
        for (int nt = 0; nt < 4; ++nt) {
          const ushort_t* kp =
              kf + ((size_t)(bh * 64 + kt * 4 + nt) * 2 + ks) * 1024 + lane * 8;
          short8 Kh = *(const short8*)kp;
          short8 Kl = *(const short8*)(kp + 512);
          Sacc[nt] = __builtin_amdgcn_mfma_f32_16x16x32_bf16(Qh[ks], Kh, Sacc[nt], 0, 0, 0);
          Sacc[nt] = __builtin_amdgcn_mfma_f32_16x16x32_bf16(Ql[ks], Kh, Sacc[nt], 0, 0, 0);
          Sacc[nt] = __builtin_amdgcn_mfma_f32_16x16x32_bf16(Qh[ks], Kl, Sacc[nt], 0, 0, 0);
        }

      // bias from LDS in C/D pattern (2-way max -> conflict-free)
      float bias_v[4][4];
#pragma unroll
      for (int nt = 0; nt < 4; ++nt)
#pragma unroll
        for (int r = 0; r < 4; ++r)
          bias_v[nt][r] = bb[((lane >> 4) * 4 + r) * 68 + nt * 16 + (lane & 15)];

      // scale + bias + key mask; tile row-max
      float Sv[4][4];
      float mt[4] = {-__builtin_inff(), -__builtin_inff(), -__builtin_inff(), -__builtin_inff()};
#pragma unroll
      for (int nt = 0; nt < 4; ++nt) {
        const bool kv = (km_cur >> (nt * 16 + (lane & 15))) & 1ull;
#pragma unroll
        for (int r = 0; r < 4; ++r) {
          float s = kv ? Sacc[nt][r] * SCALE + bias_v[nt][r] : -__builtin_inff();
          Sv[nt][r] = s;
          mt[r] = fmaxf(mt[r], s);
        }
      }
#pragma unroll
      for (int off = 1; off < 16; off <<= 1)
#pragma unroll
        for (int r = 0; r < 4; ++r) mt[r] = fmaxf(mt[r], __shfl_xor(mt[r], off));

      // online-softmax update + P split-bf16 scatter into per-wave LDS frags
      float alpha[4], lt[4];
#pragma unroll
      for (int r = 0; r < 4; ++r) {
        const float mn = fmaxf(m_run[r], mt[r]);
        alpha[r] = __expf(m_run[r] - mn);
        m_run[r] = mn;
        lt[r] = 0.f;
      }
#pragma unroll
      for (int nt = 0; nt < 4; ++nt) {
        const int ksp    = nt >> 1;
        const int key_in = (nt & 1) * 16 + (lane & 15);
        const int lane_p = 16 * (key_in >> 3);
        const int j      = key_in & 7;
#pragma unroll
        for (int r = 0; r < 4; ++r) {
          const float p = __expf(Sv[nt][r] - m_run[r]);
          lt[r] += p;
          const uint32 ph = bf16rn(p);
          const uint32 pl = bf16rn(p - bf16up(ph));
          const int lp = ((lane >> 4) * 4 + r) + lane_p;
          pb[(ksp * 2 + 0) * 512 + lp * 8 + j] = (ushort_t)ph;
          pb[(ksp * 2 + 1) * 512 + lp * 8 + j] = (ushort_t)pl;
        }
      }
#pragma unroll
      for (int off = 1; off < 16; off <<= 1)
#pragma unroll
        for (int r = 0; r < 4; ++r) lt[r] += __shfl_xor(lt[r], off);
#pragma unroll
      for (int r = 0; r < 4; ++r) l_run[r] = l_run[r] * alpha[r] + lt[r];
#pragma unroll
      for (int dt = 0; dt < 4; ++dt)
#pragma unroll
        for (int r = 0; r < 4; ++r) Oacc[dt][r] *= alpha[r];

      // read P fragments (wave-local; lgkmcnt ordering)
      short8 Ph[2], Pl[2];
#pragma unroll
      for (int ks = 0; ks < 2; ++ks) {
        Ph[ks] = *(const short8*)&pb[(ks * 2 + 0) * 512 + lane * 8];
        Pl[ks] = *(const short8*)&pb[(ks * 2 + 1) * 512 + lane * 8];
      }

      // O += P*V (x3)
#pragma unroll
      for (int dt = 0; dt < 4; ++dt)
#pragma unroll
        for (int ks = 0; ks < 2; ++ks) {
          const ushort_t* vp =
              vf + ((size_t)(((bh * 16 + kt) * 2 + ks) * 4 + dt)) * 1024 + lane * 8;
          short8 Vh = *(const short8*)vp;
          short8 Vl = *(const short8*)(vp + 512);
          Oacc[dt] = __builtin_amdgcn_mfma_f32_16x16x32_bf16(Ph[ks], Vh, Oacc[dt], 0, 0, 0);
          Oacc[dt] = __builtin_amdgcn_mfma_f32_16x16x32_bf16(Pl[ks], Vh, Oacc[dt], 0, 0, 0);
          Oacc[dt] = __builtin_amdgcn_mfma_f32_16x16x32_bf16(Ph[ks], Vl, Oacc[dt], 0, 0, 0);
        }
    }

    km_cur = km_next;
#pragma unroll
    for (int i = 0; i < 4; ++i) breg[i] = bnext[i];
  }

  // epilogue: normalize; invalid/fully-masked queries -> 0 (nan_to_num)
#pragma unroll
  for (int r = 0; r < 4; ++r) {
    const int q = q0 + (lane >> 4) * 4 + r;
    const bool vq = lane_valid(m8, bytelay, b * Nn + q);
    const float rinv = (vq && l_run[r] > 0.f) ? (1.f / l_run[r]) : 0.f;
    float* op = outp + ((size_t)(b * Nn + q)) * Dd + h * HD + (lane & 15);
#pragma unroll
    for (int dt = 0; dt < 4; ++dt) op[dt * 16] = Oacc[dt][r] * rinv;
  }
}

// ---------------------------------------------------------------------------
extern "C" void kernel_launch(void* const* d_in, const int* in_sizes, int n_in,
                              void* d_out, int out_size, void* d_ws, size_t ws_size,
                              hipStream_t stream) {
  const float* x        = (const float*)d_in[0];
  const unsigned char* mask8 = (const unsigned char*)d_in[1];
  const float* attnbias = (const float*)d_in[2];
  const float* qkv_w    = (const float*)d_in[3];
  const float* qkv_b    = (const float*)d_in[4];
  const float* out_w    = (const float*)d_in[5];
  const float* out_b    = (const float*)d_in[6];
  float* out = (float*)d_out;

  // Workspace: 4 x 16 MB regions, recycled:
  //  A: x_conv -> qfrag -> aout_conv
  //  B: q fp32 -> kfrag -> out_wf (1 MB, after attn)
  //  C: k fp32 -> vfrag
  //  D: v fp32 -> aout fp32
  // qkv_wf (3 MB) lives in d_out, which is dead until the final GEMM.
  float* ws = (float*)d_ws;
  const size_t SEG = (size_t)Bc * Hh * Nn * HD;   // 4M floats = 16 MB
  float* A = ws;
  float* B = ws + SEG;
  float* C = ws + 2 * SEG;
  float* D = ws + 3 * SEG;

  ushort_t* x_conv    = (ushort_t*)A;
  float*    qbuf      = B;
  float*    kbuf      = C;
  float*    vbuf      = D;
  ushort_t* qfrag     = (ushort_t*)A;
  ushort_t* kfrag     = (ushort_t*)B;
  ushort_t* vfrag     = (ushort_t*)C;
  float*    aout      = D;
  ushort_t* aout_conv = (ushort_t*)A;
  ushort_t* qkv_wf    = (ushort_t*)d_out;         // 3 MB scratch in d_out
  ushort_t* out_wf    = (ushort_t*)B;             // 1 MB, after kfrag dies

  // 1) convert x and qkv_w -> fragment-tiled split bf16
  convert_split<<<2048, 256, 0, stream>>>(x, x_conv);
  convert_split<<<384, 256, 0, stream>>>(qkv_w, qkv_wf);

  // 2) QKV projection, scatter into q/k/v fp32 [B,H,N,HD]
  gemm_f<128, true><<<dim3(12, 64), 256, 0, stream>>>(
      x_conv, qkv_wf, qkv_b, nullptr, 1536, qbuf, kbuf, vbuf);

  // 3) convert q,k,v -> attention MFMA fragments
  convert_frag_qk<<<2048, 256, 0, stream>>>(qbuf, qfrag);
  convert_frag_qk<<<2048, 256, 0, stream>>>(kbuf, kfrag);
  convert_frag_v <<<2048, 256, 0, stream>>>(vbuf, vfrag);

  // 4) MFMA flash attention -> aout fp32 [B,N,D]
  attn_mfma<<<1024, 256, 0, stream>>>(
      qfrag, kfrag, vfrag, attnbias, mask8, aout);

  // 5) convert out_w and attention output; 6) output projection
  convert_split<<<128, 256, 0, stream>>>(out_w, out_wf);
  convert_split<<<2048, 256, 0, stream>>>(aout, aout_conv);
  gemm_f<64, false><<<dim3(8, 64), 256, 0, stream>>>(
      aout_conv, out_wf, out_b, out, 512, nullptr, nullptr, nullptr);
}

// Round 6
// 606.989 us; speedup vs baseline: 1.2212x; 1.2212x over previous
//
#include <hip/hip_runtime.h>
#include <math.h>

// Problem constants
constexpr int Bc  = 8;
constexpr int Nn  = 1024;
constexpr int Dd  = 512;
constexpr int Hh  = 8;
constexpr int HD  = 64;
constexpr float SCALE = 0.125f; // 1/sqrt(64)

typedef unsigned short ushort_t;
typedef unsigned int uint32;
typedef __attribute__((ext_vector_type(8))) short short8;   // 8 bf16 (4 VGPRs)
typedef __attribute__((ext_vector_type(4))) float f32x4;

// ---------------- bf16 split helpers (round-to-nearest-even) ----------------
__device__ __forceinline__ uint32 bf16rn(float x) {
  uint32 u = __float_as_uint(x);
  return (u + 0x7FFFu + ((u >> 16) & 1u)) >> 16;
}
__device__ __forceinline__ float bf16up(uint32 h) { return __uint_as_float(h << 16); }

__device__ __forceinline__ void split8(const float* xs, uint4& hi, uint4& lo) {
  uint32 h[8], l[8];
#pragma unroll
  for (int j = 0; j < 8; ++j) {
    h[j] = bf16rn(xs[j]);
    l[j] = bf16rn(xs[j] - bf16up(h[j]));
  }
  hi.x = h[0] | (h[1] << 16); hi.y = h[2] | (h[3] << 16);
  hi.z = h[4] | (h[5] << 16); hi.w = h[6] | (h[7] << 16);
  lo.x = l[0] | (l[1] << 16); lo.y = l[2] | (l[3] << 16);
  lo.z = l[4] | (l[5] << 16); lo.w = l[6] | (l[7] << 16);
}

// async global->LDS, 16B per lane: lane i's 16B land at lds_base + i*16
__device__ __forceinline__ void load_lds16(const void* g, void* l) {
  __builtin_amdgcn_global_load_lds(
      (const __attribute__((address_space(1))) unsigned int*)g,
      (__attribute__((address_space(3))) unsigned int*)l, 16, 0, 0);
}

// node_valid_mask may arrive as 1-byte bool or 4-byte int/float.
__device__ __forceinline__ bool lane_valid(const unsigned char* m8, bool bytelay, int idx) {
  if (bytelay) return m8[idx] != 0;
  return ((const int*)m8)[idx] != 0;
}

// ---------------------------------------------------------------------------
// Convert two fp32 [R][512] tensors -> MFMA-fragment-tiled split bf16:
// layout [R/16][16 ksteps][2 hi/lo][512] ushort. n1 = 64-elem groups in s1.
// ---------------------------------------------------------------------------
__global__ __launch_bounds__(256) void conv_split2(
    const float* __restrict__ s1, ushort_t* __restrict__ d1, int n1,
    const float* __restrict__ s2, ushort_t* __restrict__ d2)
{
  const int t    = blockIdx.x * 256 + threadIdx.x;
  const int lane = t & 63;
  int blk = t >> 6;
  const float* src = s1; ushort_t* dst = d1;
  if (blk >= n1) { blk -= n1; src = s2; dst = d2; }

  const int rt  = blk >> 4, ks = blk & 15;
  const int row = rt * 16 + (lane & 15);
  const int k   = ks * 32 + (lane >> 4) * 8;

  const float* s = src + (size_t)row * 512 + k;
  float4 a = *(const float4*)s, b = *(const float4*)(s + 4);
  float xs[8] = {a.x, a.y, a.z, a.w, b.x, b.y, b.z, b.w};
  uint4 hi, lo; split8(xs, hi, lo);

  ushort_t* d = dst + (size_t)blk * 1024 + lane * 8;
  *(uint4*)d = hi;
  *(uint4*)(d + 512) = lo;
}

// ---------------------------------------------------------------------------
// Convert q/k fp32 [rows][64] into A/B-operand fragment tiles:
// [rows/16][2 ks][2 hl][512] ushort.
// ---------------------------------------------------------------------------
__global__ __launch_bounds__(256) void convert_frag_qk(
    const float* __restrict__ src, ushort_t* __restrict__ dst)
{
  const int t    = blockIdx.x * 256 + threadIdx.x;
  const int lane = t & 63;
  const int fid  = t >> 6;           // tile*2 + ks
  const int tile = fid >> 1, ks = fid & 1;
  const int row  = tile * 16 + (lane & 15);
  const int d    = ks * 32 + (lane >> 4) * 8;

  const float* s = src + (size_t)row * HD + d;
  float4 a = *(const float4*)s, b = *(const float4*)(s + 4);
  float xs[8] = {a.x, a.y, a.z, a.w, b.x, b.y, b.z, b.w};
  uint4 hi, lo; split8(xs, hi, lo);

  ushort_t* dp = dst + (size_t)fid * 1024 + lane * 8;
  *(uint4*)dp = hi;
  *(uint4*)(dp + 512) = lo;
}

// ---------------------------------------------------------------------------
// Convert v fp32 [bh][1024 key][64 d] into PV B-operand fragments:
// [bh][16 kt][2 ks][4 dt][2 hl][512].
// ---------------------------------------------------------------------------
__global__ __launch_bounds__(256) void convert_frag_v(
    const float* __restrict__ src, ushort_t* __restrict__ dst)
{
  const int t    = blockIdx.x * 256 + threadIdx.x;
  const int lane = t & 63;
  const int fid  = t >> 6;           // ((bh*16+kt)*2+ks)*4+dt
  const int dt   = fid & 3;
  const int ks   = (fid >> 2) & 1;
  const int kt   = (fid >> 3) & 15;
  const int bh   = fid >> 7;
  const int d    = dt * 16 + (lane & 15);
  const int key0 = kt * 64 + ks * 32 + (lane >> 4) * 8;

  const float* s = src + ((size_t)bh * Nn + key0) * HD + d;
  float xs[8];
#pragma unroll
  for (int j = 0; j < 8; ++j) xs[j] = s[(size_t)j * HD];
  uint4 hi, lo; split8(xs, hi, lo);

  ushort_t* dp = dst + (size_t)fid * 1024 + lane * 8;
  *(uint4*)dp = hi;
  *(uint4*)(dp + 512) = lo;
}

// ---------------------------------------------------------------------------
// bf16x3 MFMA GEMM, both operands pre-fragged: C = A[Mx512]*W[Ncolsx512]^T + b.
// Block: 128 x BN C tile, 256 threads = 4 waves (2x2). Staging via async
// global_load_lds (16B/lane, wave-uniform LDS base). SCATTER -> q/k/v.
// ---------------------------------------------------------------------------
template<int BN, bool SCATTER>
__global__ __launch_bounds__(256) void gemm_f(
    const ushort_t* __restrict__ Ac, const ushort_t* __restrict__ Bfrag,
    const float* __restrict__ bias, float* __restrict__ C, int Ncols,
    float* __restrict__ qb, float* __restrict__ kb, float* __restrict__ vb)
{
  constexpr int NT   = BN / 32;        // col tiles per wave (2 or 4)
  constexpr int BCH  = (BN / 16) * 2;  // B chunks per kt
  __shared__ ushort_t Ablk[16 * 512];
  __shared__ ushort_t Bblk[BCH * 512];

  const int t = threadIdx.x, lane = t & 63, w = t >> 6;
  const int wr = w >> 1, wc = w & 1;
  const int j0 = blockIdx.x * BN, i0 = blockIdx.y * 128;

  f32x4 acc[4][NT];
#pragma unroll
  for (int a = 0; a < 4; ++a)
#pragma unroll
    for (int b = 0; b < NT; ++b) acc[a][b] = (f32x4){0.f, 0.f, 0.f, 0.f};

  for (int kt = 0; kt < 16; ++kt) {
    __syncthreads();
    // async stage A (16 chunks) + B (BCH chunks), 1 KB each
    for (int c = w; c < 16 + BCH; c += 4) {
      const ushort_t* src;
      ushort_t* dst;
      if (c < 16) {
        const int rt = c >> 1, hl = c & 1;
        src = Ac + ((size_t)((i0 >> 4) + rt) * 16 + kt) * 1024 + hl * 512 + lane * 8;
        dst = Ablk + c * 512;
      } else {
        const int cb = c - 16, bt = cb >> 1, hl = cb & 1;
        src = Bfrag + ((size_t)((j0 >> 4) + bt) * 16 + kt) * 1024 + hl * 512 + lane * 8;
        dst = Bblk + cb * 512;
      }
      load_lds16(src, dst);
    }
    __syncthreads();   // vmcnt drain + barrier

    const ushort_t* Ab = Ablk + (size_t)(wr * 4) * 1024 + lane * 8;
    short8 Ah[4], Al[4];
#pragma unroll
    for (int ti = 0; ti < 4; ++ti) {
      Ah[ti] = *(const short8*)(Ab + ti * 1024);
      Al[ti] = *(const short8*)(Ab + ti * 1024 + 512);
    }
#pragma unroll
    for (int ct = 0; ct < NT; ++ct) {
      const ushort_t* Bb = Bblk + (size_t)(wc * NT + ct) * 1024 + lane * 8;
      short8 Bh = *(const short8*)Bb;
      short8 Bl = *(const short8*)(Bb + 512);
#pragma unroll
      for (int ti = 0; ti < 4; ++ti) {
        acc[ti][ct] = __builtin_amdgcn_mfma_f32_16x16x32_bf16(Ah[ti], Bh, acc[ti][ct], 0, 0, 0);
        acc[ti][ct] = __builtin_amdgcn_mfma_f32_16x16x32_bf16(Al[ti], Bh, acc[ti][ct], 0, 0, 0);
        acc[ti][ct] = __builtin_amdgcn_mfma_f32_16x16x32_bf16(Ah[ti], Bl, acc[ti][ct], 0, 0, 0);
      }
    }
  }

  const int rbase = i0 + wr * 64 + (lane >> 4) * 4;
  const int cb0   = j0 + wc * (NT * 16) + (lane & 15);
#pragma unroll
  for (int ct = 0; ct < NT; ++ct) {
    const int col = cb0 + ct * 16;
    const float bv = bias[col];
    float* dst = nullptr;
    if (SCATTER) {
      const int s = col >> 9, h = (col >> 6) & 7;
      dst  = (s == 0) ? qb : (s == 1) ? kb : vb;
      dst += (size_t)h * Nn * HD + (col & 63);
    }
#pragma unroll
    for (int ti = 0; ti < 4; ++ti) {
      const int r0 = rbase + ti * 16;
#pragma unroll
      for (int r = 0; r < 4; ++r) {
        const float v = acc[ti][ct][r] + bv;
        const int row = r0 + r;
        if (SCATTER) {
          const int b2 = row >> 10, n = row & 1023;
          dst[((size_t)b2 * Hh * Nn + n) * HD] = v;
        } else {
          C[(size_t)row * Ncols + col] = v;
        }
      }
    }
  }
}

// ---------------------------------------------------------------------------
// MFMA flash attention (R4 structure). Block = (bh, 64-q tile); 4 independent
// waves, no __syncthreads. Bias: 4 coalesced float4 loads issued before the
// S-MFMA chain (latency hidden), redistributed to C/D pattern via per-wave
// padded LDS tile. NO cross-iteration double-buffering (R5 spilled).
// ---------------------------------------------------------------------------
__global__ __launch_bounds__(256) void attn_mfma(
    const ushort_t* __restrict__ qf, const ushort_t* __restrict__ kf,
    const ushort_t* __restrict__ vf, const float* __restrict__ bias,
    const unsigned char* __restrict__ m8, float* __restrict__ outp)
{
  __shared__ float sbuf[4][2][1088];   // [wave][0 = bias 16x68 | 1 = P frags]

  const int t = threadIdx.x, lane = t & 63, w = t >> 6;
  const int bx = blockIdx.x;
  const int qt = bx & 15, bh = bx >> 4;
  const int b = bh >> 3, h = bh & 7;
  const int tt = qt * 4 + w;           // 16-query tile: 0..63
  const int q0 = tt * 16;
  const bool bytelay = (m8[1] != 0);

  // Q fragments (held for the whole kernel)
  short8 Qh[2], Ql[2];
#pragma unroll
  for (int ks = 0; ks < 2; ++ks) {
    const ushort_t* qp = qf + ((size_t)(bh * 64 + tt) * 2 + ks) * 1024 + lane * 8;
    Qh[ks] = *(const short8*)qp;
    Ql[ks] = *(const short8*)(qp + 512);
  }

  f32x4 Oacc[4];
#pragma unroll
  for (int dt = 0; dt < 4; ++dt) Oacc[dt] = (f32x4){0.f, 0.f, 0.f, 0.f};
  float m_run[4], l_run[4];
#pragma unroll
  for (int r = 0; r < 4; ++r) { m_run[r] = -__builtin_inff(); l_run[r] = 0.f; }

  float*    bb = &sbuf[w][0][0];
  ushort_t* pb = (ushort_t*)&sbuf[w][1][0];

  // bias base: row q0+(lane>>4)*4, col (lane&15)*4
  const float* bp0 = bias + ((size_t)bh * Nn + q0 + (lane >> 4) * 4) * Nn + (lane & 15) * 4;

  for (int kt = 0; kt < 16; ++kt) {
    const bool kvme = lane_valid(m8, bytelay, b * Nn + kt * 64 + lane);
    const unsigned long long kmask = __ballot(kvme);
    if (kmask == 0ull) continue;       // wave-uniform

    // coalesced bias loads; consumed after the S chain (latency hidden)
    float4 breg[4];
    {
      const float* bp = bp0 + (size_t)kt * 64;
#pragma unroll
      for (int i = 0; i < 4; ++i) breg[i] = *(const float4*)(bp + (size_t)i * Nn);
    }

    // S = Q*K^T (x3)
    f32x4 Sacc[4];
#pragma unroll
    for (int nt = 0; nt < 4; ++nt) Sacc[nt] = (f32x4){0.f, 0.f, 0.f, 0.f};
#pragma unroll
    for (int ks = 0; ks < 2; ++ks)
#pragma unroll
      for (int nt = 0; nt < 4; ++nt) {
        const ushort_t* kp =
            kf + ((size_t)(bh * 64 + kt * 4 + nt) * 2 + ks) * 1024 + lane * 8;
        short8 Kh = *(const short8*)kp;
        short8 Kl = *(const short8*)(kp + 512);
        Sacc[nt] = __builtin_amdgcn_mfma_f32_16x16x32_bf16(Qh[ks], Kh, Sacc[nt], 0, 0, 0);
        Sacc[nt] = __builtin_amdgcn_mfma_f32_16x16x32_bf16(Ql[ks], Kh, Sacc[nt], 0, 0, 0);
        Sacc[nt] = __builtin_amdgcn_mfma_f32_16x16x32_bf16(Qh[ks], Kl, Sacc[nt], 0, 0, 0);
      }

    // bias regs -> LDS (coalesced layout [row][68]) -> C/D pattern
#pragma unroll
    for (int i = 0; i < 4; ++i)
      *(float4*)&bb[((lane >> 4) * 4 + i) * 68 + (lane & 15) * 4] = breg[i];
    float bias_v[4][4];
#pragma unroll
    for (int nt = 0; nt < 4; ++nt)
#pragma unroll
      for (int r = 0; r < 4; ++r)
        bias_v[nt][r] = bb[((lane >> 4) * 4 + r) * 68 + nt * 16 + (lane & 15)];

    // scale + bias + key mask; tile row-max
    float Sv[4][4];
    float mt[4] = {-__builtin_inff(), -__builtin_inff(), -__builtin_inff(), -__builtin_inff()};
#pragma unroll
    for (int nt = 0; nt < 4; ++nt) {
      const bool kv = (kmask >> (nt * 16 + (lane & 15))) & 1ull;
#pragma unroll
      for (int r = 0; r < 4; ++r) {
        float s = kv ? Sacc[nt][r] * SCALE + bias_v[nt][r] : -__builtin_inff();
        Sv[nt][r] = s;
        mt[r] = fmaxf(mt[r], s);
      }
    }
#pragma unroll
    for (int off = 1; off < 16; off <<= 1)
#pragma unroll
      for (int r = 0; r < 4; ++r) mt[r] = fmaxf(mt[r], __shfl_xor(mt[r], off));

    // online-softmax update + P split-bf16 scatter into per-wave LDS frags
    float alpha[4], lt[4];
#pragma unroll
    for (int r = 0; r < 4; ++r) {
      const float mn = fmaxf(m_run[r], mt[r]);
      alpha[r] = __expf(m_run[r] - mn);
      m_run[r] = mn;
      lt[r] = 0.f;
    }
#pragma unroll
    for (int nt = 0; nt < 4; ++nt) {
      const int ksp    = nt >> 1;
      const int key_in = (nt & 1) * 16 + (lane & 15);
      const int lane_p = 16 * (key_in >> 3);
      const int j      = key_in & 7;
#pragma unroll
      for (int r = 0; r < 4; ++r) {
        const float p = __expf(Sv[nt][r] - m_run[r]);
        lt[r] += p;
        const uint32 ph = bf16rn(p);
        const uint32 pl = bf16rn(p - bf16up(ph));
        const int lp = ((lane >> 4) * 4 + r) + lane_p;
        pb[(ksp * 2 + 0) * 512 + lp * 8 + j] = (ushort_t)ph;
        pb[(ksp * 2 + 1) * 512 + lp * 8 + j] = (ushort_t)pl;
      }
    }
#pragma unroll
    for (int off = 1; off < 16; off <<= 1)
#pragma unroll
      for (int r = 0; r < 4; ++r) lt[r] += __shfl_xor(lt[r], off);
#pragma unroll
    for (int r = 0; r < 4; ++r) l_run[r] = l_run[r] * alpha[r] + lt[r];
#pragma unroll
    for (int dt = 0; dt < 4; ++dt)
#pragma unroll
      for (int r = 0; r < 4; ++r) Oacc[dt][r] *= alpha[r];

    // read P fragments (wave-local; lgkmcnt ordering)
    short8 Ph[2], Pl[2];
#pragma unroll
    for (int ks = 0; ks < 2; ++ks) {
      Ph[ks] = *(const short8*)&pb[(ks * 2 + 0) * 512 + lane * 8];
      Pl[ks] = *(const short8*)&pb[(ks * 2 + 1) * 512 + lane * 8];
    }

    // O += P*V (x3)
#pragma unroll
    for (int dt = 0; dt < 4; ++dt)
#pragma unroll
      for (int ks = 0; ks < 2; ++ks) {
        const ushort_t* vp =
            vf + ((size_t)(((bh * 16 + kt) * 2 + ks) * 4 + dt)) * 1024 + lane * 8;
        short8 Vh = *(const short8*)vp;
        short8 Vl = *(const short8*)(vp + 512);
        Oacc[dt] = __builtin_amdgcn_mfma_f32_16x16x32_bf16(Ph[ks], Vh, Oacc[dt], 0, 0, 0);
        Oacc[dt] = __builtin_amdgcn_mfma_f32_16x16x32_bf16(Pl[ks], Vh, Oacc[dt], 0, 0, 0);
        Oacc[dt] = __builtin_amdgcn_mfma_f32_16x16x32_bf16(Ph[ks], Vl, Oacc[dt], 0, 0, 0);
      }
  }

  // epilogue: normalize; invalid/fully-masked queries -> 0 (nan_to_num)
#pragma unroll
  for (int r = 0; r < 4; ++r) {
    const int q = q0 + (lane >> 4) * 4 + r;
    const bool vq = lane_valid(m8, bytelay, b * Nn + q);
    const float rinv = (vq && l_run[r] > 0.f) ? (1.f / l_run[r]) : 0.f;
    float* op = outp + ((size_t)(b * Nn + q)) * Dd + h * HD + (lane & 15);
#pragma unroll
    for (int dt = 0; dt < 4; ++dt) op[dt * 16] = Oacc[dt][r] * rinv;
  }
}

// ---------------------------------------------------------------------------
extern "C" void kernel_launch(void* const* d_in, const int* in_sizes, int n_in,
                              void* d_out, int out_size, void* d_ws, size_t ws_size,
                              hipStream_t stream) {
  const float* x        = (const float*)d_in[0];
  const unsigned char* mask8 = (const unsigned char*)d_in[1];
  const float* attnbias = (const float*)d_in[2];
  const float* qkv_w    = (const float*)d_in[3];
  const float* qkv_b    = (const float*)d_in[4];
  const float* out_w    = (const float*)d_in[5];
  const float* out_b    = (const float*)d_in[6];
  float* out = (float*)d_out;

  // Workspace: 4 x 16 MB regions, recycled:
  //  A: x_conv -> qfrag -> aout_conv
  //  B: q fp32 -> kfrag -> out_wf
  //  C: k fp32 -> vfrag
  //  D: v fp32 -> aout fp32
  // qkv_wf (3 MB) lives in d_out (dead until the final GEMM writes it).
  float* ws = (float*)d_ws;
  const size_t SEG = (size_t)Bc * Hh * Nn * HD;   // 4M floats = 16 MB
  float* A = ws;
  float* B = ws + SEG;
  float* C = ws + 2 * SEG;
  float* D = ws + 3 * SEG;

  ushort_t* x_conv    = (ushort_t*)A;
  float*    qbuf      = B;
  float*    kbuf      = C;
  float*    vbuf      = D;
  ushort_t* qfrag     = (ushort_t*)A;
  ushort_t* kfrag     = (ushort_t*)B;
  ushort_t* vfrag     = (ushort_t*)C;
  float*    aout      = D;
  ushort_t* aout_conv = (ushort_t*)A;
  ushort_t* qkv_wf    = (ushort_t*)d_out;
  ushort_t* out_wf    = (ushort_t*)B;

  // 1) convert x (8192 groups) + qkv_w (1536 groups) -> split-bf16 frags
  conv_split2<<<(8192 + 1536) / 4, 256, 0, stream>>>(
      x, x_conv, 8192, qkv_w, qkv_wf);

  // 2) QKV projection, scatter into q/k/v fp32 [B,H,N,HD]
  gemm_f<128, true><<<dim3(12, 64), 256, 0, stream>>>(
      x_conv, qkv_wf, qkv_b, nullptr, 1536, qbuf, kbuf, vbuf);

  // 3) convert q,k,v -> attention MFMA fragments (sequential: region reuse)
  convert_frag_qk<<<2048, 256, 0, stream>>>(qbuf, qfrag);
  convert_frag_qk<<<2048, 256, 0, stream>>>(kbuf, kfrag);
  convert_frag_v <<<2048, 256, 0, stream>>>(vbuf, vfrag);

  // 4) MFMA flash attention -> aout fp32 [B,N,D]
  attn_mfma<<<1024, 256, 0, stream>>>(
      qfrag, kfrag, vfrag, attnbias, mask8, aout);

  // 5) convert aout (8192 groups) + out_w (512 groups)
  conv_split2<<<(8192 + 512) / 4, 256, 0, stream>>>(
      aout, aout_conv, 8192, out_w, out_wf);

  // 6) output projection -> d_out
  gemm_f<64, false><<<dim3(8, 64), 256, 0, stream>>>(
      aout_conv, out_wf, out_b, out, 512, nullptr, nullptr, nullptr);
}